// Round 5
// baseline (274.610 us; speedup 1.0000x reference)
//
#include <hip/hip_runtime.h>

// FullyConnectedTensorProduct: irreps 64x(0e+1o+2e) x same -> same, N=4096.
// out[z, OFF[io] + w*(2lo+1) + k] = (1/24) * sum_p sum_{u,v,i,j} W[p][u][v][w]*CG_p[i,j,k]*x1[z,u,i]*x2[z,v,j]
//
// R4 = R3 architecture (kout-merged units, u split across 4 waves, pre-swizzled W chunks,
// double-buffered global_load_lds staging) with ONE revert for bisect: A-fragment pack
// uses the R2-proven scalar f2bf instead of v_cvt_pk_bf16_f32 inline asm.

typedef unsigned short u16;
typedef __attribute__((ext_vector_type(8))) short bf16x8;   // 8 bf16 in 4 VGPRs
typedef __attribute__((ext_vector_type(4))) float f32x4;

#define NZ 4096
#define ROWE 832   // padded bf16 elems per z-row: seg0 64*1 + seg1 64*4 + seg2 64*8

__device__ __forceinline__ u16 f2bf(float x) {               // RNE f32->bf16
    unsigned u = __float_as_uint(x);
    return (u16)((u + 0x7FFFu + ((u >> 16) & 1u)) >> 16);
}
__device__ __forceinline__ float bf2f(u16 b) {
    return __uint_as_float(((unsigned)b) << 16);
}

// ---------------- Clebsch-Gordan tables (real basis, reference phase conventions) ----
struct CGE { int i, j, k; float c; };
template<int P> struct CGT;
template<> struct CGT<0> { static constexpr int n=1; static constexpr CGE e[1]={{0,0,0,1.0f}}; };
template<> struct CGT<1> { static constexpr int n=3; static constexpr CGE e[3]={
    {0,0,0,0.5773502691896258f},{1,1,0,0.5773502691896258f},{2,2,0,0.5773502691896258f}}; };
template<> struct CGT<2> { static constexpr int n=5; static constexpr CGE e[5]={
    {0,0,0,0.4472135954999579f},{1,1,0,0.4472135954999579f},{2,2,0,0.4472135954999579f},
    {3,3,0,0.4472135954999579f},{4,4,0,0.4472135954999579f}}; };
template<> struct CGT<3> { static constexpr int n=3; static constexpr CGE e[3]={
    {0,0,0,1.0f},{0,1,1,1.0f},{0,2,2,1.0f}}; };
template<> struct CGT<4> { static constexpr int n=3; static constexpr CGE e[3]={
    {0,0,0,1.0f},{1,0,1,1.0f},{2,0,2,1.0f}}; };
template<> struct CGT<5> { static constexpr int n=11; static constexpr CGE e[11]={
    {0,2,0,-0.31622776601683794f},{1,1,0,0.5477225575051661f},{0,4,0,-0.5477225575051661f},{2,0,0,0.5477225575051661f},
    {0,1,1,0.5477225575051661f},{2,3,1,0.5477225575051661f},{1,2,1,0.6324555320336759f},
    {2,2,2,-0.31622776601683794f},{1,3,2,0.5477225575051661f},{0,0,2,0.5477225575051661f},{2,4,2,0.5477225575051661f}}; };
template<> struct CGT<6> { static constexpr int n=11; static constexpr CGE e[11]={
    {2,0,0,-0.31622776601683794f},{1,1,0,0.5477225575051661f},{4,0,0,-0.5477225575051661f},{0,2,0,0.5477225575051661f},
    {1,0,1,0.5477225575051661f},{3,2,1,0.5477225575051661f},{2,1,1,0.6324555320336759f},
    {2,2,2,-0.31622776601683794f},{3,1,2,0.5477225575051661f},{0,0,2,0.5477225575051661f},{4,2,2,0.5477225575051661f}}; };
template<> struct CGT<7> { static constexpr int n=5; static constexpr CGE e[5]={
    {0,0,0,1.0f},{0,1,1,1.0f},{0,2,2,1.0f},{0,3,3,1.0f},{0,4,4,1.0f}}; };
template<> struct CGT<8> { static constexpr int n=11; static constexpr CGE e[11]={
    {0,2,0,0.7071067811865476f},{2,0,0,0.7071067811865476f},
    {0,1,1,0.7071067811865476f},{1,0,1,0.7071067811865476f},
    {0,0,2,-0.4082482904638630f},{1,1,2,0.8164965809277260f},{2,2,2,-0.4082482904638630f},
    {1,2,3,0.7071067811865476f},{2,1,3,0.7071067811865476f},
    {0,0,4,-0.7071067811865476f},{2,2,4,0.7071067811865476f}}; };
template<> struct CGT<9> { static constexpr int n=5; static constexpr CGE e[5]={
    {0,0,0,1.0f},{1,0,1,1.0f},{2,0,2,1.0f},{3,0,3,1.0f},{4,0,4,1.0f}}; };
template<> struct CGT<10> { static constexpr int n=25; static constexpr CGE e[25]={
    {0,2,0,-0.5345224838248488f},{2,0,0,-0.5345224838248488f},{1,3,0,0.4629100498862757f},{3,1,0,0.4629100498862757f},
    {0,3,1,0.4629100498862757f},{3,0,1,0.4629100498862757f},{1,4,1,-0.4629100498862757f},{4,1,1,-0.4629100498862757f},
    {1,2,1,0.2672612419124244f},{2,1,1,0.2672612419124244f},
    {0,0,2,-0.5345224838248488f},{1,1,2,0.2672612419124244f},{2,2,2,0.5345224838248488f},{3,3,2,0.2672612419124244f},{4,4,2,-0.5345224838248488f},
    {0,1,3,0.4629100498862757f},{1,0,3,0.4629100498862757f},{3,4,3,0.4629100498862757f},{4,3,3,0.4629100498862757f},
    {2,3,3,0.2672612419124244f},{3,2,3,0.2672612419124244f},
    {1,1,4,-0.4629100498862757f},{3,3,4,0.4629100498862757f},{2,4,4,-0.5345224838248488f},{4,2,4,-0.5345224838248488f}}; };

// ---------------- padded x layout helpers ----------------
template<int SEG>
__device__ __forceinline__ int soff(int m) {
    if constexpr (SEG == 0) return m;              // width 1
    else if constexpr (SEG == 1) return 64 + 4*m;  // width 3 padded to 4
    else return 320 + 8*m;                         // width 5 padded to 8
}
template<int L>
__device__ __forceinline__ void load_xvec(const u16* p, float* o) {
    if constexpr (L == 0) {
        o[0] = bf2f(p[0]);
    } else if constexpr (L == 1) {
        uint2 r = *reinterpret_cast<const uint2*>(p);
        o[0] = bf2f((u16)(r.x & 0xffff)); o[1] = bf2f((u16)(r.x >> 16)); o[2] = bf2f((u16)(r.y & 0xffff));
    } else {
        uint4 r = *reinterpret_cast<const uint4*>(p);
        o[0] = bf2f((u16)(r.x & 0xffff)); o[1] = bf2f((u16)(r.x >> 16));
        o[2] = bf2f((u16)(r.y & 0xffff)); o[3] = bf2f((u16)(r.y >> 16));
        o[4] = bf2f((u16)(r.z & 0xffff));
    }
}

// ---------------- LDS staging: one chunk = 32 KiB = {1 u per wave-quarter} ----------
// Wt layout: chunk g = pid*16 + c holds u in {q*16+c, q=0..3}; sub-chunk q is 8 KiB.
// 16B unit (w, ms=h*4+kb) at slot q*512 + w*8 + (ms ^ (w&7)); conflict-free on read.
__device__ __forceinline__ void stage_chunk(const u16* __restrict__ Wtb, int g,
                                            u16* lbuf, int tid) {
    const u16* src = Wtb + ((size_t)g << 14);
    #pragma unroll
    for (int qq = 0; qq < 8; ++qq) {
        const int off = qq*2048 + tid*8;       // 16B per thread, lane-linear
        __builtin_amdgcn_global_load_lds(
            (const __attribute__((address_space(1))) void*)(const void*)(src + off),
            (__attribute__((address_space(3))) void*)(void*)(lbuf + off),
            16, 0, 0);
    }
}

// ---------------- one u (one chunk) from LDS: KO kouts share the B-fragments --------
template<int PID, int S1, int S2, int KO>
__device__ __forceinline__ void chunk_compute(const u16* __restrict__ lbuf,
                                              const float (&a1)[2*S1+1],
                                              const float (&b2)[16][2*S2+1],
                                              f32x4 (&acc)[KO][4], int lane, int uq) {
    const int kb = lane >> 4, nl = lane & 15;
    float pre[CGT<PID>::n];
    #pragma unroll
    for (int t = 0; t < CGT<PID>::n; ++t)
        pre[t] = CGT<PID>::e[t].c * a1[CGT<PID>::e[t].i];
    #pragma unroll
    for (int h = 0; h < 2; ++h) {
        bf16x8 bf[4];
        #pragma unroll
        for (int nf = 0; nf < 4; ++nf) {
            const int w = nf*16 + nl;
            const int slot = uq*512 + w*8 + ((h*4 + kb) ^ (w & 7));
            bf[nf] = *reinterpret_cast<const bf16x8*>(lbuf + slot*8);
        }
        #pragma unroll
        for (int ko = 0; ko < KO; ++ko) {
            bf16x8 af;                                  // R2-proven scalar pack (bisect)
            #pragma unroll
            for (int e = 0; e < 8; ++e) {
                float v = 0.f;
                #pragma unroll
                for (int t = 0; t < CGT<PID>::n; ++t)
                    if (CGT<PID>::e[t].k == ko)
                        v += pre[t] * b2[h*8 + e][CGT<PID>::e[t].j];
                af[e] = (short)f2bf(v);
            }
            #pragma unroll
            for (int nf = 0; nf < 4; ++nf)
                acc[ko][nf] = __builtin_amdgcn_mfma_f32_16x16x32_bf16(af, bf[nf], acc[ko][nf], 0, 0, 0);
        }
    }
}

// ---------------- one path: 16 chunks (u = uq*16 + c), double-buffered staging ------
template<int PID, int S1, int S2, int KO>
__device__ __forceinline__ void run_path_m(const u16* __restrict__ x1r, const u16* __restrict__ x2r,
                                           const u16* __restrict__ Wtb, u16* lds,
                                           f32x4 (&acc)[KO][4], int lane, int tid, int uq,
                                           int& q, int nchunks, int gbase) {
    constexpr int D1 = 2*S1 + 1, D2 = 2*S2 + 1;
    const int kb = lane >> 4;
    float b2[16][D2];
    #pragma unroll
    for (int h = 0; h < 2; ++h)
        #pragma unroll
        for (int e = 0; e < 8; ++e)
            load_xvec<S2>(x2r + soff<S2>(h*32 + kb*8 + e), b2[h*8 + e]);

    float a1[D1], a1n[D1];
    load_xvec<S1>(x1r + soff<S1>(uq*16), a1);
    for (int c = 0; c < 16; ++c) {
        __syncthreads();                          // chunk q staged; all readers past q^1
        if (q + 1 < nchunks)
            stage_chunk(Wtb, gbase + q + 1, lds + (((q + 1) & 1) << 14), tid);
        load_xvec<S1>(x1r + soff<S1>(uq*16 + ((c + 1) & 15)), a1n);   // prefetch next u
        chunk_compute<PID,S1,S2,KO>(lds + ((q & 1) << 14), a1, b2, acc, lane, uq);
        #pragma unroll
        for (int d = 0; d < D1; ++d) a1[d] = a1n[d];
        ++q;
    }
}

// ---------------- one unit = (ztile16, io): all kouts, u split across 4 waves -------
template<int IO>
__device__ __forceinline__ void run_unit(const u16* __restrict__ XB1, const u16* __restrict__ XB2,
                                         const u16* __restrict__ Wtb, float* __restrict__ out,
                                         int zt, u16* lds) {
    constexpr int KO = 2*IO + 1;
    constexpr int NP = (IO == 0) ? 3 : 4;
    constexpr int GB = (IO == 0) ? 0 : (IO == 1 ? 48 : 112);   // first pid * 16
    constexpr int OFFI = (IO == 0) ? 0 : (IO == 1 ? 64 : 256);
    const int tid = threadIdx.x;
    const int lane = tid & 63, uq = tid >> 6;     // wave = u-quarter
    const int zin = zt*16 + (lane & 15);
    const u16* x1r = XB1 + (size_t)zin*ROWE;
    const u16* x2r = XB2 + (size_t)zin*ROWE;
    f32x4 acc[KO][4];
    #pragma unroll
    for (int k = 0; k < KO; ++k)
        #pragma unroll
        for (int nf = 0; nf < 4; ++nf) acc[k][nf] = (f32x4){0.f, 0.f, 0.f, 0.f};

    int q = 0;
    stage_chunk(Wtb, GB, lds, tid);               // prologue: chunk 0 -> buf 0

    if constexpr (IO == 0) {
        run_path_m<0,0,0,KO>(x1r, x2r, Wtb, lds, acc, lane, tid, uq, q, NP*16, GB);
        run_path_m<1,1,1,KO>(x1r, x2r, Wtb, lds, acc, lane, tid, uq, q, NP*16, GB);
        run_path_m<2,2,2,KO>(x1r, x2r, Wtb, lds, acc, lane, tid, uq, q, NP*16, GB);
    } else if constexpr (IO == 1) {
        run_path_m<3,0,1,KO>(x1r, x2r, Wtb, lds, acc, lane, tid, uq, q, NP*16, GB);
        run_path_m<4,1,0,KO>(x1r, x2r, Wtb, lds, acc, lane, tid, uq, q, NP*16, GB);
        run_path_m<5,1,2,KO>(x1r, x2r, Wtb, lds, acc, lane, tid, uq, q, NP*16, GB);
        run_path_m<6,2,1,KO>(x1r, x2r, Wtb, lds, acc, lane, tid, uq, q, NP*16, GB);
    } else {
        run_path_m<7,0,2,KO>(x1r, x2r, Wtb, lds, acc, lane, tid, uq, q, NP*16, GB);
        run_path_m<8,1,1,KO>(x1r, x2r, Wtb, lds, acc, lane, tid, uq, q, NP*16, GB);
        run_path_m<9,2,0,KO>(x1r, x2r, Wtb, lds, acc, lane, tid, uq, q, NP*16, GB);
        run_path_m<10,2,2,KO>(x1r, x2r, Wtb, lds, acc, lane, tid, uq, q, NP*16, GB);
    }

    // ---- cross-wave (u-quarter) reduction via LDS, then store (wave 0) ----
    __syncthreads();
    float* red = reinterpret_cast<float*>(lds);   // reuse staging buffers (<= 61.4 KB)
    if (uq > 0) {
        const int base = ((uq - 1)*64 + lane) * (KO*16);
        #pragma unroll
        for (int k = 0; k < KO; ++k)
            #pragma unroll
            for (int nf = 0; nf < 4; ++nf)
                #pragma unroll
                for (int r = 0; r < 4; ++r)
                    red[base + (k*4 + nf)*4 + r] = acc[k][nf][r];
    }
    __syncthreads();
    if (uq == 0) {
        const int nl = lane & 15;
        const int zoutb = zt*16 + (lane >> 4)*4;
        #pragma unroll
        for (int k = 0; k < KO; ++k)
            #pragma unroll
            for (int nf = 0; nf < 4; ++nf) {
                f32x4 s = acc[k][nf];
                #pragma unroll
                for (int wv = 1; wv < 4; ++wv) {
                    const int base = ((wv - 1)*64 + lane) * (KO*16) + (k*4 + nf)*4;
                    #pragma unroll
                    for (int r = 0; r < 4; ++r) s[r] += red[base + r];
                }
                const int wcol = nf*16 + nl;
                #pragma unroll
                for (int r = 0; r < 4; ++r)
                    out[(size_t)(zoutb + r)*576 + OFFI + wcol*KO + k] = s[r] * 0.041666666666666664f;
            }
    }
}

__global__ __launch_bounds__(256) void tp_main(const u16* __restrict__ XB1, const u16* __restrict__ XB2,
                                               const u16* __restrict__ Wtb, float* __restrict__ out) {
    __shared__ u16 smem[2*16384];                 // 64 KiB: dbuf staging / reduce scratch
    const int io = blockIdx.x % 3;
    const int zt = blockIdx.x / 3;
    if (io == 0)      run_unit<0>(XB1, XB2, Wtb, out, zt, smem);
    else if (io == 1) run_unit<1>(XB1, XB2, Wtb, out, zt, smem);
    else              run_unit<2>(XB1, XB2, Wtb, out, zt, smem);
}

// ---------------- prep kernels ----------------
// x -> padded bf16 rows [z][ROWE]
__global__ void prep_x(const float* __restrict__ x1, const float* __restrict__ x2,
                       u16* __restrict__ XB1, u16* __restrict__ XB2) {
    int g = blockIdx.x * 256 + threadIdx.x;
    const int PER = NZ * 192;
    if (g >= 2*PER) return;
    const float* src; u16* dst;
    if (g < PER) { src = x1; dst = XB1; } else { src = x2; dst = XB2; g -= PER; }
    const int zz = g / 192, s = g - zz*192, seg = s >> 6, m = s & 63;
    const float* sp = src + zz*576;
    u16* dp = dst + zz*ROWE;
    if (seg == 0) {
        dp[m] = f2bf(sp[m]);
    } else if (seg == 1) {
        u16 t0 = f2bf(sp[64 + m*3 + 0]);
        u16 t1 = f2bf(sp[64 + m*3 + 1]);
        u16 t2 = f2bf(sp[64 + m*3 + 2]);
        uint2 pk; pk.x = (unsigned)t0 | ((unsigned)t1 << 16); pk.y = (unsigned)t2;
        *reinterpret_cast<uint2*>(dp + 64 + m*4) = pk;
    } else {
        u16 t[5];
        #pragma unroll
        for (int c = 0; c < 5; ++c) t[c] = f2bf(sp[256 + m*5 + c]);
        uint4 pk;
        pk.x = (unsigned)t[0] | ((unsigned)t[1] << 16);
        pk.y = (unsigned)t[2] | ((unsigned)t[3] << 16);
        pk.z = (unsigned)t[4];
        pk.w = 0u;
        *reinterpret_cast<uint4*>(dp + 320 + m*8) = pk;
    }
}

// W[p][u][v][w] f32 -> chunked/swizzled bf16:
// chunk g = p*16 + (u&15); sub-chunk q = u>>4 (512 16B-units);
// unit (w, ms=h*4+kb) at slot q*512 + w*8 + (ms ^ (w&7)), holding W[p][u][h*32+kb*8+e][w].
__global__ void prep_w(const float* __restrict__ W, u16* __restrict__ Wtb) {
    __shared__ float ld[4096];
    const int b = blockIdx.x;            // 0..703 : (p,u)
    const int p = b >> 6, u = b & 63;
    const int tid = threadIdx.x;
    const float* src = W + ((size_t)(p*64 + u) << 12);
    #pragma unroll
    for (int i = 0; i < 16; ++i) ld[tid + i*256] = src[tid + i*256];   // coalesced
    __syncthreads();
    const int g  = p*16 + (u & 15);
    const int q_ = u >> 4;
    #pragma unroll
    for (int r = 0; r < 2; ++r) {
        const int j = r*256 + tid;                 // 512 16B-units for this (p,u)
        const int w = j & 63, ms = j >> 6;         // ms = h*4+kb in [0,8)
        const int h = ms >> 2, kb = ms & 3;
        const int vb = h*32 + kb*8;
        u16 tmp[8];
        #pragma unroll
        for (int e = 0; e < 8; ++e) tmp[e] = f2bf(ld[(vb + e)*64 + w]);
        const int unit = q_*512 + w*8 + (ms ^ (w & 7));
        uint4 pk;
        pk.x = (unsigned)tmp[0] | ((unsigned)tmp[1] << 16);
        pk.y = (unsigned)tmp[2] | ((unsigned)tmp[3] << 16);
        pk.z = (unsigned)tmp[4] | ((unsigned)tmp[5] << 16);
        pk.w = (unsigned)tmp[6] | ((unsigned)tmp[7] << 16);
        *reinterpret_cast<uint4*>(Wtb + (((size_t)g*2048 + unit))*8) = pk;
    }
}

extern "C" void kernel_launch(void* const* d_in, const int* in_sizes, int n_in,
                              void* d_out, int out_size, void* d_ws, size_t ws_size,
                              hipStream_t stream) {
    const float* x1 = (const float*)d_in[0];
    const float* x2 = (const float*)d_in[1];
    const float* W  = (const float*)d_in[2];
    float* out = (float*)d_out;

    u16* XB1 = (u16*)d_ws;                 // 4096*832*2  = 6.8 MB
    u16* XB2 = XB1 + NZ*ROWE;              // 6.8 MB
    u16* Wtb = XB2 + NZ*ROWE;              // 11*16*2048*8*2 = 5.8 MB
    if (ws_size < (size_t)(2*NZ*ROWE + 11*16*2048*8) * sizeof(u16)) return;

    hipLaunchKernelGGL(prep_x, dim3((2*NZ*192 + 255)/256), dim3(256), 0, stream, x1, x2, XB1, XB2);
    hipLaunchKernelGGL(prep_w, dim3(11*64), dim3(256), 0, stream, W, Wtb);
    hipLaunchKernelGGL(tp_main, dim3(256*3), dim3(256), 0, stream, XB1, XB2, Wtb, out);
}

// Round 6
// 227.666 us; speedup vs baseline: 1.2062x; 1.2062x over previous
//
#include <hip/hip_runtime.h>

// FullyConnectedTensorProduct: irreps 64x(0e+1o+2e) x same -> same, N=4096.
// out[z, OFF[io] + w*(2lo+1) + k] = (1/24) * sum_p sum_{u,v,i,j} W[p][u][v][w]*CG_p[i,j,k]*x1[z,u,i]*x2[z,v,j]
//
// R6: kout-merged units with ZT=64 (4 z-waves/block) and u-range split ACROSS blocks
// (US=4 quarters); all waves consume every staged 32 KiB chunk (4 u), so W staging
// traffic = (4096/64)*5.8MB = 372 MB (R5: 1.5 GB) and per-chunk compute covers the
// staging latency. u-quarter partials -> f32 workspace -> deterministic reduce kernel.
// No intra-block reduction (eliminates R5's 32-way-conflict epilogue).

typedef unsigned short u16;
typedef __attribute__((ext_vector_type(8))) short bf16x8;   // 8 bf16 in 4 VGPRs
typedef __attribute__((ext_vector_type(4))) float f32x4;

#define NZ 4096
#define ROWE 832   // padded bf16 elems per z-row: seg0 64*1 + seg1 64*4 + seg2 64*8

__device__ __forceinline__ u16 f2bf(float x) {               // RNE f32->bf16
    unsigned u = __float_as_uint(x);
    return (u16)((u + 0x7FFFu + ((u >> 16) & 1u)) >> 16);
}
__device__ __forceinline__ float bf2f(u16 b) {
    return __uint_as_float(((unsigned)b) << 16);
}

// ---------------- Clebsch-Gordan tables (real basis, reference phase conventions) ----
struct CGE { int i, j, k; float c; };
template<int P> struct CGT;
template<> struct CGT<0> { static constexpr int n=1; static constexpr CGE e[1]={{0,0,0,1.0f}}; };
template<> struct CGT<1> { static constexpr int n=3; static constexpr CGE e[3]={
    {0,0,0,0.5773502691896258f},{1,1,0,0.5773502691896258f},{2,2,0,0.5773502691896258f}}; };
template<> struct CGT<2> { static constexpr int n=5; static constexpr CGE e[5]={
    {0,0,0,0.4472135954999579f},{1,1,0,0.4472135954999579f},{2,2,0,0.4472135954999579f},
    {3,3,0,0.4472135954999579f},{4,4,0,0.4472135954999579f}}; };
template<> struct CGT<3> { static constexpr int n=3; static constexpr CGE e[3]={
    {0,0,0,1.0f},{0,1,1,1.0f},{0,2,2,1.0f}}; };
template<> struct CGT<4> { static constexpr int n=3; static constexpr CGE e[3]={
    {0,0,0,1.0f},{1,0,1,1.0f},{2,0,2,1.0f}}; };
template<> struct CGT<5> { static constexpr int n=11; static constexpr CGE e[11]={
    {0,2,0,-0.31622776601683794f},{1,1,0,0.5477225575051661f},{0,4,0,-0.5477225575051661f},{2,0,0,0.5477225575051661f},
    {0,1,1,0.5477225575051661f},{2,3,1,0.5477225575051661f},{1,2,1,0.6324555320336759f},
    {2,2,2,-0.31622776601683794f},{1,3,2,0.5477225575051661f},{0,0,2,0.5477225575051661f},{2,4,2,0.5477225575051661f}}; };
template<> struct CGT<6> { static constexpr int n=11; static constexpr CGE e[11]={
    {2,0,0,-0.31622776601683794f},{1,1,0,0.5477225575051661f},{4,0,0,-0.5477225575051661f},{0,2,0,0.5477225575051661f},
    {1,0,1,0.5477225575051661f},{3,2,1,0.5477225575051661f},{2,1,1,0.6324555320336759f},
    {2,2,2,-0.31622776601683794f},{3,1,2,0.5477225575051661f},{0,0,2,0.5477225575051661f},{4,2,2,0.5477225575051661f}}; };
template<> struct CGT<7> { static constexpr int n=5; static constexpr CGE e[5]={
    {0,0,0,1.0f},{0,1,1,1.0f},{0,2,2,1.0f},{0,3,3,1.0f},{0,4,4,1.0f}}; };
template<> struct CGT<8> { static constexpr int n=11; static constexpr CGE e[11]={
    {0,2,0,0.7071067811865476f},{2,0,0,0.7071067811865476f},
    {0,1,1,0.7071067811865476f},{1,0,1,0.7071067811865476f},
    {0,0,2,-0.4082482904638630f},{1,1,2,0.8164965809277260f},{2,2,2,-0.4082482904638630f},
    {1,2,3,0.7071067811865476f},{2,1,3,0.7071067811865476f},
    {0,0,4,-0.7071067811865476f},{2,2,4,0.7071067811865476f}}; };
template<> struct CGT<9> { static constexpr int n=5; static constexpr CGE e[5]={
    {0,0,0,1.0f},{1,0,1,1.0f},{2,0,2,1.0f},{3,0,3,1.0f},{4,0,4,1.0f}}; };
template<> struct CGT<10> { static constexpr int n=25; static constexpr CGE e[25]={
    {0,2,0,-0.5345224838248488f},{2,0,0,-0.5345224838248488f},{1,3,0,0.4629100498862757f},{3,1,0,0.4629100498862757f},
    {0,3,1,0.4629100498862757f},{3,0,1,0.4629100498862757f},{1,4,1,-0.4629100498862757f},{4,1,1,-0.4629100498862757f},
    {1,2,1,0.2672612419124244f},{2,1,1,0.2672612419124244f},
    {0,0,2,-0.5345224838248488f},{1,1,2,0.2672612419124244f},{2,2,2,0.5345224838248488f},{3,3,2,0.2672612419124244f},{4,4,2,-0.5345224838248488f},
    {0,1,3,0.4629100498862757f},{1,0,3,0.4629100498862757f},{3,4,3,0.4629100498862757f},{4,3,3,0.4629100498862757f},
    {2,3,3,0.2672612419124244f},{3,2,3,0.2672612419124244f},
    {1,1,4,-0.4629100498862757f},{3,3,4,0.4629100498862757f},{2,4,4,-0.5345224838248488f},{4,2,4,-0.5345224838248488f}}; };

// ---------------- padded x layout helpers ----------------
template<int SEG>
__device__ __forceinline__ int soff(int m) {
    if constexpr (SEG == 0) return m;              // width 1
    else if constexpr (SEG == 1) return 64 + 4*m;  // width 3 padded to 4
    else return 320 + 8*m;                         // width 5 padded to 8
}
template<int L>
__device__ __forceinline__ void load_xvec(const u16* p, float* o) {
    if constexpr (L == 0) {
        o[0] = bf2f(p[0]);
    } else if constexpr (L == 1) {
        uint2 r = *reinterpret_cast<const uint2*>(p);
        o[0] = bf2f((u16)(r.x & 0xffff)); o[1] = bf2f((u16)(r.x >> 16)); o[2] = bf2f((u16)(r.y & 0xffff));
    } else {
        uint4 r = *reinterpret_cast<const uint4*>(p);
        o[0] = bf2f((u16)(r.x & 0xffff)); o[1] = bf2f((u16)(r.x >> 16));
        o[2] = bf2f((u16)(r.y & 0xffff)); o[3] = bf2f((u16)(r.y >> 16));
        o[4] = bf2f((u16)(r.z & 0xffff));
    }
}

// ---------------- LDS staging: one chunk = 4 consecutive u = 32 KiB (R2 layout) -----
// Wt layout: chunk g = pid*16 + (u>>2); 16B unit (w, m=(u&3)*8+h*4+kb) at slot
// w*32 + (m ^ (w&31)). Measured conflict-free on ds_read_b128 (R2: 0 conflicts).
__device__ __forceinline__ void stage_chunk(const u16* __restrict__ Wtb, int g,
                                            u16* lbuf, int tid) {
    const u16* src = Wtb + ((size_t)g << 14);
    #pragma unroll
    for (int qq = 0; qq < 8; ++qq) {
        const int off = qq*2048 + tid*8;       // 16B per thread, lane-linear
        __builtin_amdgcn_global_load_lds(
            (const __attribute__((address_space(1))) void*)(const void*)(src + off),
            (__attribute__((address_space(3))) void*)(void*)(lbuf + off),
            16, 0, 0);
    }
}

// ---------------- one chunk (4 u), consumed by every z-wave; KO kouts share B-frags -
template<int PID, int S1, int S2, int KO>
__device__ __forceinline__ void chunk_compute(const u16* __restrict__ lbuf,
                                              const u16* __restrict__ x1r,
                                              const float (&b2)[16][2*S2+1],
                                              int u0, f32x4 (&acc)[KO][4], int lane) {
    const int kb = lane >> 4, nl = lane & 15;
    float a1[4][2*S1+1];
    #pragma unroll
    for (int uu = 0; uu < 4; ++uu)
        load_xvec<S1>(x1r + soff<S1>(u0 + uu), a1[uu]);
    #pragma unroll
    for (int uu = 0; uu < 4; ++uu) {
        float pre[CGT<PID>::n];
        #pragma unroll
        for (int t = 0; t < CGT<PID>::n; ++t)
            pre[t] = CGT<PID>::e[t].c * a1[uu][CGT<PID>::e[t].i];
        #pragma unroll
        for (int h = 0; h < 2; ++h) {
            bf16x8 bf[4];
            #pragma unroll
            for (int nf = 0; nf < 4; ++nf) {
                const int w = nf*16 + nl;
                const int slot = w*32 + ((uu*8 + h*4 + kb) ^ (w & 31));
                bf[nf] = *reinterpret_cast<const bf16x8*>(lbuf + slot*8);
            }
            #pragma unroll
            for (int ko = 0; ko < KO; ++ko) {
                bf16x8 af;
                #pragma unroll
                for (int e = 0; e < 8; ++e) {
                    float v = 0.f;
                    #pragma unroll
                    for (int t = 0; t < CGT<PID>::n; ++t)
                        if (CGT<PID>::e[t].k == ko)
                            v += pre[t] * b2[h*8 + e][CGT<PID>::e[t].j];
                    af[e] = (short)f2bf(v);
                }
                #pragma unroll
                for (int nf = 0; nf < 4; ++nf)
                    acc[ko][nf] = __builtin_amdgcn_mfma_f32_16x16x32_bf16(af, bf[nf], acc[ko][nf], 0, 0, 0);
            }
        }
    }
}

// ---------------- one path: CPP chunks (u = uq*CPP*4 + c*4 ...), dbuf staging -------
template<int PID, int S1, int S2, int KO, int CPP>
__device__ __forceinline__ void run_path(const u16* __restrict__ x1r, const u16* __restrict__ x2r,
                                         const u16* __restrict__ Wtb, u16* lds,
                                         f32x4 (&acc)[KO][4], int lane, int tid, int uq,
                                         int& q, int nq, int GB) {
    constexpr int D2 = 2*S2 + 1;
    const int kb = lane >> 4;
    float b2[16][D2];
    #pragma unroll
    for (int h = 0; h < 2; ++h)
        #pragma unroll
        for (int e = 0; e < 8; ++e)
            load_xvec<S2>(x2r + soff<S2>(h*32 + kb*8 + e), b2[h*8 + e]);

    const int ubase = uq*(CPP*4);
    for (int c = 0; c < CPP; ++c) {
        __syncthreads();                          // chunk q staged (vmcnt drained)
        if (q + 1 < nq) {
            const int qn = q + 1;
            const int g = GB + (qn/CPP)*16 + uq*CPP + (qn%CPP);   // CPP is pow2
            stage_chunk(Wtb, g, lds + ((qn & 1) << 14), tid);
        }
        chunk_compute<PID,S1,S2,KO>(lds + ((q & 1) << 14), x1r, b2, ubase + c*4, acc, lane);
        ++q;
    }
}

// ---------------- one unit = (ztile64, io, uq): partials or direct out --------------
template<int IO, int US>
__device__ __forceinline__ void run_unit(const u16* __restrict__ XB1, const u16* __restrict__ XB2,
                                         const u16* __restrict__ Wtb, float* __restrict__ dst,
                                         int zt, int uq, u16* lds) {
    constexpr int KO   = 2*IO + 1;
    constexpr int NP   = (IO == 0) ? 3 : 4;
    constexpr int GB   = (IO == 0) ? 0 : (IO == 1 ? 48 : 112);   // first pid * 16
    constexpr int OFFI = (IO == 0) ? 0 : (IO == 1 ? 64 : 256);
    constexpr int CPP  = 16/US;                   // chunks per path in this block
    const int tid = threadIdx.x;
    const int lane = tid & 63, wave = tid >> 6;   // wave = z-subtile
    const int zin = zt*64 + wave*16 + (lane & 15);
    const u16* x1r = XB1 + (size_t)zin*ROWE;
    const u16* x2r = XB2 + (size_t)zin*ROWE;
    f32x4 acc[KO][4];
    #pragma unroll
    for (int k = 0; k < KO; ++k)
        #pragma unroll
        for (int nf = 0; nf < 4; ++nf) acc[k][nf] = (f32x4){0.f, 0.f, 0.f, 0.f};

    int q = 0;
    stage_chunk(Wtb, GB + uq*CPP, lds, tid);      // prologue: chunk 0 -> buf 0

    if constexpr (IO == 0) {
        run_path<0,0,0,KO,CPP>(x1r, x2r, Wtb, lds, acc, lane, tid, uq, q, NP*CPP, GB);
        run_path<1,1,1,KO,CPP>(x1r, x2r, Wtb, lds, acc, lane, tid, uq, q, NP*CPP, GB);
        run_path<2,2,2,KO,CPP>(x1r, x2r, Wtb, lds, acc, lane, tid, uq, q, NP*CPP, GB);
    } else if constexpr (IO == 1) {
        run_path<3,0,1,KO,CPP>(x1r, x2r, Wtb, lds, acc, lane, tid, uq, q, NP*CPP, GB);
        run_path<4,1,0,KO,CPP>(x1r, x2r, Wtb, lds, acc, lane, tid, uq, q, NP*CPP, GB);
        run_path<5,1,2,KO,CPP>(x1r, x2r, Wtb, lds, acc, lane, tid, uq, q, NP*CPP, GB);
        run_path<6,2,1,KO,CPP>(x1r, x2r, Wtb, lds, acc, lane, tid, uq, q, NP*CPP, GB);
    } else {
        run_path<7,0,2,KO,CPP>(x1r, x2r, Wtb, lds, acc, lane, tid, uq, q, NP*CPP, GB);
        run_path<8,1,1,KO,CPP>(x1r, x2r, Wtb, lds, acc, lane, tid, uq, q, NP*CPP, GB);
        run_path<9,2,0,KO,CPP>(x1r, x2r, Wtb, lds, acc, lane, tid, uq, q, NP*CPP, GB);
        run_path<10,2,2,KO,CPP>(x1r, x2r, Wtb, lds, acc, lane, tid, uq, q, NP*CPP, GB);
    }

    // epilogue: C/D layout col=lane&15 (w), row=(lane>>4)*4+reg (z); no LDS reduction
    const int nl = lane & 15;
    const int zoutb = zt*64 + wave*16 + (lane >> 4)*4;
    #pragma unroll
    for (int k = 0; k < KO; ++k)
        #pragma unroll
        for (int nf = 0; nf < 4; ++nf) {
            const int wcol = nf*16 + nl;
            #pragma unroll
            for (int r = 0; r < 4; ++r) {
                const size_t idx = (size_t)(zoutb + r)*576 + OFFI + wcol*KO + k;
                if constexpr (US == 1) dst[idx] = acc[k][nf][r] * 0.041666666666666664f;
                else                   dst[idx] = acc[k][nf][r];
            }
        }
}

template<int US>
__global__ __launch_bounds__(256) void tp_main(const u16* __restrict__ XB1, const u16* __restrict__ XB2,
                                               const u16* __restrict__ Wtb, float* __restrict__ dst) {
    __shared__ u16 smem[2*16384];                 // 64 KiB, double-buffered 32 KiB chunks
    const int per = 3*US;
    const int zt  = blockIdx.x / per;
    const int rr  = blockIdx.x % per;
    const int io  = rr / US;
    const int uq  = rr % US;
    float* dstP = (US == 1) ? dst : dst + (size_t)uq*NZ*576;
    if (io == 0)      run_unit<0,US>(XB1, XB2, Wtb, dstP, zt, uq, smem);
    else if (io == 1) run_unit<1,US>(XB1, XB2, Wtb, dstP, zt, uq, smem);
    else              run_unit<2,US>(XB1, XB2, Wtb, dstP, zt, uq, smem);
}

// ---------------- partial-sum reduction (deterministic, f32) ------------------------
template<int US>
__global__ __launch_bounds__(256) void reduce_k(const float* __restrict__ P, float* __restrict__ out) {
    const int i = blockIdx.x*256 + threadIdx.x;   // float4 index; grid sized exactly
    float4 s = reinterpret_cast<const float4*>(P)[i];
    #pragma unroll
    for (int u = 1; u < US; ++u) {
        float4 t = reinterpret_cast<const float4*>(P + (size_t)u*NZ*576)[i];
        s.x += t.x; s.y += t.y; s.z += t.z; s.w += t.w;
    }
    const float sc = 0.041666666666666664f;
    float4 o; o.x = s.x*sc; o.y = s.y*sc; o.z = s.z*sc; o.w = s.w*sc;
    reinterpret_cast<float4*>(out)[i] = o;
}

// ---------------- prep kernels ----------------
// x -> padded bf16 rows [z][ROWE]
__global__ void prep_x(const float* __restrict__ x1, const float* __restrict__ x2,
                       u16* __restrict__ XB1, u16* __restrict__ XB2) {
    int g = blockIdx.x * 256 + threadIdx.x;
    const int PER = NZ * 192;
    if (g >= 2*PER) return;
    const float* src; u16* dst;
    if (g < PER) { src = x1; dst = XB1; } else { src = x2; dst = XB2; g -= PER; }
    const int zz = g / 192, s = g - zz*192, seg = s >> 6, m = s & 63;
    const float* sp = src + zz*576;
    u16* dp = dst + zz*ROWE;
    if (seg == 0) {
        dp[m] = f2bf(sp[m]);
    } else if (seg == 1) {
        u16 t0 = f2bf(sp[64 + m*3 + 0]);
        u16 t1 = f2bf(sp[64 + m*3 + 1]);
        u16 t2 = f2bf(sp[64 + m*3 + 2]);
        uint2 pk; pk.x = (unsigned)t0 | ((unsigned)t1 << 16); pk.y = (unsigned)t2;
        *reinterpret_cast<uint2*>(dp + 64 + m*4) = pk;
    } else {
        u16 t[5];
        #pragma unroll
        for (int c = 0; c < 5; ++c) t[c] = f2bf(sp[256 + m*5 + c]);
        uint4 pk;
        pk.x = (unsigned)t[0] | ((unsigned)t[1] << 16);
        pk.y = (unsigned)t[2] | ((unsigned)t[3] << 16);
        pk.z = (unsigned)t[4];
        pk.w = 0u;
        *reinterpret_cast<uint4*>(dp + 320 + m*8) = pk;
    }
}

// W[p][u][v][w] f32 -> chunked/swizzled bf16 (R2-proven layout):
// chunk g = p*16 + (u>>2); 16B unit (w, m=(u&3)*8 + h*4 + kb) at slot w*32 + (m^(w&31)),
// holding W[p][u][h*32+kb*8+e][w] for e=0..7.
__global__ void prep_w(const float* __restrict__ W, u16* __restrict__ Wtb) {
    __shared__ float ld[4096];
    const int b = blockIdx.x;            // 0..703 : (p,u)
    const int p = b >> 6, u = b & 63;
    const int tid = threadIdx.x;
    const float* src = W + ((size_t)(p*64 + u) << 12);
    #pragma unroll
    for (int i = 0; i < 16; ++i) ld[tid + i*256] = src[tid + i*256];   // coalesced
    __syncthreads();
    const int c = u >> 2, uu = u & 3;
    #pragma unroll
    for (int r = 0; r < 2; ++r) {
        const int j = r*256 + tid;                 // 512 16B-units for this (p,u)
        const int w = j & 63, ms = j >> 6;         // ms = h*4+kb in [0,8)
        const int m = uu*8 + ms;
        const int h = ms >> 2, kb = ms & 3;
        const int vb = h*32 + kb*8;
        u16 tmp[8];
        #pragma unroll
        for (int e = 0; e < 8; ++e) tmp[e] = f2bf(ld[(vb + e)*64 + w]);
        const int s_ = w*32 + (m ^ (w & 31));
        uint4 pk;
        pk.x = (unsigned)tmp[0] | ((unsigned)tmp[1] << 16);
        pk.y = (unsigned)tmp[2] | ((unsigned)tmp[3] << 16);
        pk.z = (unsigned)tmp[4] | ((unsigned)tmp[5] << 16);
        pk.w = (unsigned)tmp[6] | ((unsigned)tmp[7] << 16);
        *reinterpret_cast<uint4*>(Wtb + ((((size_t)(p*16 + c)) << 11) + s_)*8) = pk;
    }
}

extern "C" void kernel_launch(void* const* d_in, const int* in_sizes, int n_in,
                              void* d_out, int out_size, void* d_ws, size_t ws_size,
                              hipStream_t stream) {
    const float* x1 = (const float*)d_in[0];
    const float* x2 = (const float*)d_in[1];
    const float* W  = (const float*)d_in[2];
    float* out = (float*)d_out;

    u16* XB1 = (u16*)d_ws;                 // 4096*832*2  = 6.8 MB
    u16* XB2 = XB1 + NZ*ROWE;              // 6.8 MB
    u16* Wtb = XB2 + NZ*ROWE;              // 11*16*2048*8*2 = 5.8 MB
    const size_t baseu = (size_t)2*NZ*ROWE + (size_t)11*16*2048*8;   // u16 elems
    if (ws_size < baseu*2) return;
    float* Pbuf = (float*)(XB1 + baseu);   // 16B-aligned (baseu*2 % 16 == 0)
    const size_t avail = ws_size - baseu*2;
    const size_t psz = (size_t)NZ*576*4;   // one partial slab, 9.4 MB
    const int US = (avail >= 4*psz) ? 4 : (avail >= 2*psz) ? 2 : 1;

    hipLaunchKernelGGL(prep_x, dim3((2*NZ*192 + 255)/256), dim3(256), 0, stream, x1, x2, XB1, XB2);
    hipLaunchKernelGGL(prep_w, dim3(11*64), dim3(256), 0, stream, W, Wtb);

    const int RED_GRID = NZ*576/4/256;     // 2304, exact
    if (US == 4) {
        hipLaunchKernelGGL(tp_main<4>, dim3(64*12), dim3(256), 0, stream, XB1, XB2, Wtb, Pbuf);
        hipLaunchKernelGGL(reduce_k<4>, dim3(RED_GRID), dim3(256), 0, stream, Pbuf, out);
    } else if (US == 2) {
        hipLaunchKernelGGL(tp_main<2>, dim3(64*6), dim3(256), 0, stream, XB1, XB2, Wtb, Pbuf);
        hipLaunchKernelGGL(reduce_k<2>, dim3(RED_GRID), dim3(256), 0, stream, Pbuf, out);
    } else {
        hipLaunchKernelGGL(tp_main<1>, dim3(64*3), dim3(256), 0, stream, XB1, XB2, Wtb, out);
    }
}

// Round 7
// 179.036 us; speedup vs baseline: 1.5338x; 1.2716x over previous
//
#include <hip/hip_runtime.h>
#include <hip/hip_bf16.h>

// FullyConnectedTensorProduct: irreps 64x(0e+1o+2e) x same -> same, N=4096.
// out[z, OFF[io] + w*(2lo+1) + k] = (1/24) * sum_p sum_{u,v,i,j} W[p][u][v][w]*CG_p[i,j,k]*x1[z,u,i]*x2[z,v,j]
//
// R7 = R6 (kout-merged units, ZT=64, u-split across blocks US=4, partials+reduce)
// + native v_cvt_pk_bf16_f32 A-frag pack via __float22bfloat162_rn (NOT inline asm)
// + io2-first block ordering (longest blocks dispatch first).

typedef unsigned short u16;
typedef __attribute__((ext_vector_type(8))) short bf16x8;   // 8 bf16 in 4 VGPRs
typedef __attribute__((ext_vector_type(4))) float f32x4;

#define NZ 4096
#define ROWE 832   // padded bf16 elems per z-row: seg0 64*1 + seg1 64*4 + seg2 64*8

__device__ __forceinline__ u16 f2bf(float x) {               // RNE f32->bf16 (prep only)
    unsigned u = __float_as_uint(x);
    return (u16)((u + 0x7FFFu + ((u >> 16) & 1u)) >> 16);
}
__device__ __forceinline__ float bf2f(u16 b) {
    return __uint_as_float(((unsigned)b) << 16);
}

// ---------------- Clebsch-Gordan tables (real basis, reference phase conventions) ----
struct CGE { int i, j, k; float c; };
template<int P> struct CGT;
template<> struct CGT<0> { static constexpr int n=1; static constexpr CGE e[1]={{0,0,0,1.0f}}; };
template<> struct CGT<1> { static constexpr int n=3; static constexpr CGE e[3]={
    {0,0,0,0.5773502691896258f},{1,1,0,0.5773502691896258f},{2,2,0,0.5773502691896258f}}; };
template<> struct CGT<2> { static constexpr int n=5; static constexpr CGE e[5]={
    {0,0,0,0.4472135954999579f},{1,1,0,0.4472135954999579f},{2,2,0,0.4472135954999579f},
    {3,3,0,0.4472135954999579f},{4,4,0,0.4472135954999579f}}; };
template<> struct CGT<3> { static constexpr int n=3; static constexpr CGE e[3]={
    {0,0,0,1.0f},{0,1,1,1.0f},{0,2,2,1.0f}}; };
template<> struct CGT<4> { static constexpr int n=3; static constexpr CGE e[3]={
    {0,0,0,1.0f},{1,0,1,1.0f},{2,0,2,1.0f}}; };
template<> struct CGT<5> { static constexpr int n=11; static constexpr CGE e[11]={
    {0,2,0,-0.31622776601683794f},{1,1,0,0.5477225575051661f},{0,4,0,-0.5477225575051661f},{2,0,0,0.5477225575051661f},
    {0,1,1,0.5477225575051661f},{2,3,1,0.5477225575051661f},{1,2,1,0.6324555320336759f},
    {2,2,2,-0.31622776601683794f},{1,3,2,0.5477225575051661f},{0,0,2,0.5477225575051661f},{2,4,2,0.5477225575051661f}}; };
template<> struct CGT<6> { static constexpr int n=11; static constexpr CGE e[11]={
    {2,0,0,-0.31622776601683794f},{1,1,0,0.5477225575051661f},{4,0,0,-0.5477225575051661f},{0,2,0,0.5477225575051661f},
    {1,0,1,0.5477225575051661f},{3,2,1,0.5477225575051661f},{2,1,1,0.6324555320336759f},
    {2,2,2,-0.31622776601683794f},{3,1,2,0.5477225575051661f},{0,0,2,0.5477225575051661f},{4,2,2,0.5477225575051661f}}; };
template<> struct CGT<7> { static constexpr int n=5; static constexpr CGE e[5]={
    {0,0,0,1.0f},{0,1,1,1.0f},{0,2,2,1.0f},{0,3,3,1.0f},{0,4,4,1.0f}}; };
template<> struct CGT<8> { static constexpr int n=11; static constexpr CGE e[11]={
    {0,2,0,0.7071067811865476f},{2,0,0,0.7071067811865476f},
    {0,1,1,0.7071067811865476f},{1,0,1,0.7071067811865476f},
    {0,0,2,-0.4082482904638630f},{1,1,2,0.8164965809277260f},{2,2,2,-0.4082482904638630f},
    {1,2,3,0.7071067811865476f},{2,1,3,0.7071067811865476f},
    {0,0,4,-0.7071067811865476f},{2,2,4,0.7071067811865476f}}; };
template<> struct CGT<9> { static constexpr int n=5; static constexpr CGE e[5]={
    {0,0,0,1.0f},{1,0,1,1.0f},{2,0,2,1.0f},{3,0,3,1.0f},{4,0,4,1.0f}}; };
template<> struct CGT<10> { static constexpr int n=25; static constexpr CGE e[25]={
    {0,2,0,-0.5345224838248488f},{2,0,0,-0.5345224838248488f},{1,3,0,0.4629100498862757f},{3,1,0,0.4629100498862757f},
    {0,3,1,0.4629100498862757f},{3,0,1,0.4629100498862757f},{1,4,1,-0.4629100498862757f},{4,1,1,-0.4629100498862757f},
    {1,2,1,0.2672612419124244f},{2,1,1,0.2672612419124244f},
    {0,0,2,-0.5345224838248488f},{1,1,2,0.2672612419124244f},{2,2,2,0.5345224838248488f},{3,3,2,0.2672612419124244f},{4,4,2,-0.5345224838248488f},
    {0,1,3,0.4629100498862757f},{1,0,3,0.4629100498862757f},{3,4,3,0.4629100498862757f},{4,3,3,0.4629100498862757f},
    {2,3,3,0.2672612419124244f},{3,2,3,0.2672612419124244f},
    {1,1,4,-0.4629100498862757f},{3,3,4,0.4629100498862757f},{2,4,4,-0.5345224838248488f},{4,2,4,-0.5345224838248488f}}; };

// ---------------- padded x layout helpers ----------------
template<int SEG>
__device__ __forceinline__ int soff(int m) {
    if constexpr (SEG == 0) return m;              // width 1
    else if constexpr (SEG == 1) return 64 + 4*m;  // width 3 padded to 4
    else return 320 + 8*m;                         // width 5 padded to 8
}
template<int L>
__device__ __forceinline__ void load_xvec(const u16* p, float* o) {
    if constexpr (L == 0) {
        o[0] = bf2f(p[0]);
    } else if constexpr (L == 1) {
        uint2 r = *reinterpret_cast<const uint2*>(p);
        o[0] = bf2f((u16)(r.x & 0xffff)); o[1] = bf2f((u16)(r.x >> 16)); o[2] = bf2f((u16)(r.y & 0xffff));
    } else {
        uint4 r = *reinterpret_cast<const uint4*>(p);
        o[0] = bf2f((u16)(r.x & 0xffff)); o[1] = bf2f((u16)(r.x >> 16));
        o[2] = bf2f((u16)(r.y & 0xffff)); o[3] = bf2f((u16)(r.y >> 16));
        o[4] = bf2f((u16)(r.z & 0xffff));
    }
}

// ---------------- LDS staging: one chunk = 4 consecutive u = 32 KiB (R2 layout) -----
// Wt layout: chunk g = pid*16 + (u>>2); 16B unit (w, m=(u&3)*8+h*4+kb) at slot
// w*32 + (m ^ (w&31)). Measured conflict-free on ds_read_b128 (R2/R6: 0 conflicts).
__device__ __forceinline__ void stage_chunk(const u16* __restrict__ Wtb, int g,
                                            u16* lbuf, int tid) {
    const u16* src = Wtb + ((size_t)g << 14);
    #pragma unroll
    for (int qq = 0; qq < 8; ++qq) {
        const int off = qq*2048 + tid*8;       // 16B per thread, lane-linear
        __builtin_amdgcn_global_load_lds(
            (const __attribute__((address_space(1))) void*)(const void*)(src + off),
            (__attribute__((address_space(3))) void*)(void*)(lbuf + off),
            16, 0, 0);
    }
}

// ---------------- one chunk (4 u), consumed by every z-wave; KO kouts share B-frags -
template<int PID, int S1, int S2, int KO>
__device__ __forceinline__ void chunk_compute(const u16* __restrict__ lbuf,
                                              const u16* __restrict__ x1r,
                                              const float (&b2)[16][2*S2+1],
                                              int u0, f32x4 (&acc)[KO][4], int lane) {
    const int kb = lane >> 4, nl = lane & 15;
    float a1[4][2*S1+1];
    #pragma unroll
    for (int uu = 0; uu < 4; ++uu)
        load_xvec<S1>(x1r + soff<S1>(u0 + uu), a1[uu]);
    #pragma unroll
    for (int uu = 0; uu < 4; ++uu) {
        float pre[CGT<PID>::n];
        #pragma unroll
        for (int t = 0; t < CGT<PID>::n; ++t)
            pre[t] = CGT<PID>::e[t].c * a1[uu][CGT<PID>::e[t].i];
        #pragma unroll
        for (int h = 0; h < 2; ++h) {
            bf16x8 bf[4];
            #pragma unroll
            for (int nf = 0; nf < 4; ++nf) {
                const int w = nf*16 + nl;
                const int slot = w*32 + ((uu*8 + h*4 + kb) ^ (w & 31));
                bf[nf] = *reinterpret_cast<const bf16x8*>(lbuf + slot*8);
            }
            #pragma unroll
            for (int ko = 0; ko < KO; ++ko) {
                float s[8];
                #pragma unroll
                for (int e = 0; e < 8; ++e) {
                    float v = 0.f;
                    #pragma unroll
                    for (int t = 0; t < CGT<PID>::n; ++t)
                        if (CGT<PID>::e[t].k == ko)
                            v += pre[t] * b2[h*8 + e][CGT<PID>::e[t].j];
                    s[e] = v;
                }
                union { unsigned u[4]; bf16x8 v; } af;
                #pragma unroll
                for (int qq = 0; qq < 4; ++qq) {      // v_cvt_pk_bf16_f32 via HIP intrinsic
                    __hip_bfloat162 t2 = __float22bfloat162_rn(make_float2(s[2*qq], s[2*qq+1]));
                    unsigned r; __builtin_memcpy(&r, &t2, 4);
                    af.u[qq] = r;
                }
                #pragma unroll
                for (int nf = 0; nf < 4; ++nf)
                    acc[ko][nf] = __builtin_amdgcn_mfma_f32_16x16x32_bf16(af.v, bf[nf], acc[ko][nf], 0, 0, 0);
            }
        }
    }
}

// ---------------- one path: CPP chunks (u = uq*CPP*4 + c*4 ...), dbuf staging -------
template<int PID, int S1, int S2, int KO, int CPP>
__device__ __forceinline__ void run_path(const u16* __restrict__ x1r, const u16* __restrict__ x2r,
                                         const u16* __restrict__ Wtb, u16* lds,
                                         f32x4 (&acc)[KO][4], int lane, int tid, int uq,
                                         int& q, int nq, int GB) {
    constexpr int D2 = 2*S2 + 1;
    const int kb = lane >> 4;
    float b2[16][D2];
    #pragma unroll
    for (int h = 0; h < 2; ++h)
        #pragma unroll
        for (int e = 0; e < 8; ++e)
            load_xvec<S2>(x2r + soff<S2>(h*32 + kb*8 + e), b2[h*8 + e]);

    const int ubase = uq*(CPP*4);
    for (int c = 0; c < CPP; ++c) {
        __syncthreads();                          // chunk q staged (vmcnt drained)
        if (q + 1 < nq) {
            const int qn = q + 1;
            const int g = GB + (qn/CPP)*16 + uq*CPP + (qn%CPP);   // CPP is pow2
            stage_chunk(Wtb, g, lds + ((qn & 1) << 14), tid);
        }
        chunk_compute<PID,S1,S2,KO>(lds + ((q & 1) << 14), x1r, b2, ubase + c*4, acc, lane);
        ++q;
    }
}

// ---------------- one unit = (ztile64, io, uq): partials or direct out --------------
template<int IO, int US>
__device__ __forceinline__ void run_unit(const u16* __restrict__ XB1, const u16* __restrict__ XB2,
                                         const u16* __restrict__ Wtb, float* __restrict__ dst,
                                         int zt, int uq, u16* lds) {
    constexpr int KO   = 2*IO + 1;
    constexpr int NP   = (IO == 0) ? 3 : 4;
    constexpr int GB   = (IO == 0) ? 0 : (IO == 1 ? 48 : 112);   // first pid * 16
    constexpr int OFFI = (IO == 0) ? 0 : (IO == 1 ? 64 : 256);
    constexpr int CPP  = 16/US;                   // chunks per path in this block
    const int tid = threadIdx.x;
    const int lane = tid & 63, wave = tid >> 6;   // wave = z-subtile
    const int zin = zt*64 + wave*16 + (lane & 15);
    const u16* x1r = XB1 + (size_t)zin*ROWE;
    const u16* x2r = XB2 + (size_t)zin*ROWE;
    f32x4 acc[KO][4];
    #pragma unroll
    for (int k = 0; k < KO; ++k)
        #pragma unroll
        for (int nf = 0; nf < 4; ++nf) acc[k][nf] = (f32x4){0.f, 0.f, 0.f, 0.f};

    int q = 0;
    stage_chunk(Wtb, GB + uq*CPP, lds, tid);      // prologue: chunk 0 -> buf 0

    if constexpr (IO == 0) {
        run_path<0,0,0,KO,CPP>(x1r, x2r, Wtb, lds, acc, lane, tid, uq, q, NP*CPP, GB);
        run_path<1,1,1,KO,CPP>(x1r, x2r, Wtb, lds, acc, lane, tid, uq, q, NP*CPP, GB);
        run_path<2,2,2,KO,CPP>(x1r, x2r, Wtb, lds, acc, lane, tid, uq, q, NP*CPP, GB);
    } else if constexpr (IO == 1) {
        run_path<3,0,1,KO,CPP>(x1r, x2r, Wtb, lds, acc, lane, tid, uq, q, NP*CPP, GB);
        run_path<4,1,0,KO,CPP>(x1r, x2r, Wtb, lds, acc, lane, tid, uq, q, NP*CPP, GB);
        run_path<5,1,2,KO,CPP>(x1r, x2r, Wtb, lds, acc, lane, tid, uq, q, NP*CPP, GB);
        run_path<6,2,1,KO,CPP>(x1r, x2r, Wtb, lds, acc, lane, tid, uq, q, NP*CPP, GB);
    } else {
        run_path<7,0,2,KO,CPP>(x1r, x2r, Wtb, lds, acc, lane, tid, uq, q, NP*CPP, GB);
        run_path<8,1,1,KO,CPP>(x1r, x2r, Wtb, lds, acc, lane, tid, uq, q, NP*CPP, GB);
        run_path<9,2,0,KO,CPP>(x1r, x2r, Wtb, lds, acc, lane, tid, uq, q, NP*CPP, GB);
        run_path<10,2,2,KO,CPP>(x1r, x2r, Wtb, lds, acc, lane, tid, uq, q, NP*CPP, GB);
    }

    // epilogue: C/D layout col=lane&15 (w), row=(lane>>4)*4+reg (z); no LDS reduction
    const int nl = lane & 15;
    const int zoutb = zt*64 + wave*16 + (lane >> 4)*4;
    #pragma unroll
    for (int k = 0; k < KO; ++k)
        #pragma unroll
        for (int nf = 0; nf < 4; ++nf) {
            const int wcol = nf*16 + nl;
            #pragma unroll
            for (int r = 0; r < 4; ++r) {
                const size_t idx = (size_t)(zoutb + r)*576 + OFFI + wcol*KO + k;
                if constexpr (US == 1) dst[idx] = acc[k][nf][r] * 0.041666666666666664f;
                else                   dst[idx] = acc[k][nf][r];
            }
        }
}

template<int US>
__global__ __launch_bounds__(256) void tp_main(const u16* __restrict__ XB1, const u16* __restrict__ XB2,
                                               const u16* __restrict__ Wtb, float* __restrict__ dst) {
    __shared__ u16 smem[2*16384];                 // 64 KiB, double-buffered 32 KiB chunks
    const int per = 3*US;
    const int zt  = blockIdx.x / per;
    const int rr  = blockIdx.x % per;
    const int io  = 2 - rr / US;                  // io2 (longest) dispatches first
    const int uq  = rr % US;
    float* dstP = (US == 1) ? dst : dst + (size_t)uq*NZ*576;
    if (io == 0)      run_unit<0,US>(XB1, XB2, Wtb, dstP, zt, uq, smem);
    else if (io == 1) run_unit<1,US>(XB1, XB2, Wtb, dstP, zt, uq, smem);
    else              run_unit<2,US>(XB1, XB2, Wtb, dstP, zt, uq, smem);
}

// ---------------- partial-sum reduction (deterministic, f32) ------------------------
template<int US>
__global__ __launch_bounds__(256) void reduce_k(const float* __restrict__ P, float* __restrict__ out) {
    const int i = blockIdx.x*256 + threadIdx.x;   // float4 index; grid sized exactly
    float4 s = reinterpret_cast<const float4*>(P)[i];
    #pragma unroll
    for (int u = 1; u < US; ++u) {
        float4 t = reinterpret_cast<const float4*>(P + (size_t)u*NZ*576)[i];
        s.x += t.x; s.y += t.y; s.z += t.z; s.w += t.w;
    }
    const float sc = 0.041666666666666664f;
    float4 o; o.x = s.x*sc; o.y = s.y*sc; o.z = s.z*sc; o.w = s.w*sc;
    reinterpret_cast<float4*>(out)[i] = o;
}

// ---------------- prep kernels ----------------
// x -> padded bf16 rows [z][ROWE]
__global__ void prep_x(const float* __restrict__ x1, const float* __restrict__ x2,
                       u16* __restrict__ XB1, u16* __restrict__ XB2) {
    int g = blockIdx.x * 256 + threadIdx.x;
    const int PER = NZ * 192;
    if (g >= 2*PER) return;
    const float* src; u16* dst;
    if (g < PER) { src = x1; dst = XB1; } else { src = x2; dst = XB2; g -= PER; }
    const int zz = g / 192, s = g - zz*192, seg = s >> 6, m = s & 63;
    const float* sp = src + zz*576;
    u16* dp = dst + zz*ROWE;
    if (seg == 0) {
        dp[m] = f2bf(sp[m]);
    } else if (seg == 1) {
        u16 t0 = f2bf(sp[64 + m*3 + 0]);
        u16 t1 = f2bf(sp[64 + m*3 + 1]);
        u16 t2 = f2bf(sp[64 + m*3 + 2]);
        uint2 pk; pk.x = (unsigned)t0 | ((unsigned)t1 << 16); pk.y = (unsigned)t2;
        *reinterpret_cast<uint2*>(dp + 64 + m*4) = pk;
    } else {
        u16 t[5];
        #pragma unroll
        for (int c = 0; c < 5; ++c) t[c] = f2bf(sp[256 + m*5 + c]);
        uint4 pk;
        pk.x = (unsigned)t[0] | ((unsigned)t[1] << 16);
        pk.y = (unsigned)t[2] | ((unsigned)t[3] << 16);
        pk.z = (unsigned)t[4];
        pk.w = 0u;
        *reinterpret_cast<uint4*>(dp + 320 + m*8) = pk;
    }
}

// W[p][u][v][w] f32 -> chunked/swizzled bf16 (R2-proven layout):
// chunk g = p*16 + (u>>2); 16B unit (w, m=(u&3)*8 + h*4 + kb) at slot w*32 + (m^(w&31)),
// holding W[p][u][h*32+kb*8+e][w] for e=0..7.
__global__ void prep_w(const float* __restrict__ W, u16* __restrict__ Wtb) {
    __shared__ float ld[4096];
    const int b = blockIdx.x;            // 0..703 : (p,u)
    const int p = b >> 6, u = b & 63;
    const int tid = threadIdx.x;
    const float* src = W + ((size_t)(p*64 + u) << 12);
    #pragma unroll
    for (int i = 0; i < 16; ++i) ld[tid + i*256] = src[tid + i*256];   // coalesced
    __syncthreads();
    const int c = u >> 2, uu = u & 3;
    #pragma unroll
    for (int r = 0; r < 2; ++r) {
        const int j = r*256 + tid;                 // 512 16B-units for this (p,u)
        const int w = j & 63, ms = j >> 6;         // ms = h*4+kb in [0,8)
        const int m = uu*8 + ms;
        const int h = ms >> 2, kb = ms & 3;
        const int vb = h*32 + kb*8;
        u16 tmp[8];
        #pragma unroll
        for (int e = 0; e < 8; ++e) tmp[e] = f2bf(ld[(vb + e)*64 + w]);
        const int s_ = w*32 + (m ^ (w & 31));
        uint4 pk;
        pk.x = (unsigned)tmp[0] | ((unsigned)tmp[1] << 16);
        pk.y = (unsigned)tmp[2] | ((unsigned)tmp[3] << 16);
        pk.z = (unsigned)tmp[4] | ((unsigned)tmp[5] << 16);
        pk.w = (unsigned)tmp[6] | ((unsigned)tmp[7] << 16);
        *reinterpret_cast<uint4*>(Wtb + ((((size_t)(p*16 + c)) << 11) + s_)*8) = pk;
    }
}

extern "C" void kernel_launch(void* const* d_in, const int* in_sizes, int n_in,
                              void* d_out, int out_size, void* d_ws, size_t ws_size,
                              hipStream_t stream) {
    const float* x1 = (const float*)d_in[0];
    const float* x2 = (const float*)d_in[1];
    const float* W  = (const float*)d_in[2];
    float* out = (float*)d_out;

    u16* XB1 = (u16*)d_ws;                 // 4096*832*2  = 6.8 MB
    u16* XB2 = XB1 + NZ*ROWE;              // 6.8 MB
    u16* Wtb = XB2 + NZ*ROWE;              // 11*16*2048*8*2 = 5.8 MB
    const size_t baseu = (size_t)2*NZ*ROWE + (size_t)11*16*2048*8;   // u16 elems
    if (ws_size < baseu*2) return;
    float* Pbuf = (float*)(XB1 + baseu);   // 16B-aligned (baseu*2 % 16 == 0)
    const size_t avail = ws_size - baseu*2;
    const size_t psz = (size_t)NZ*576*4;   // one partial slab, 9.4 MB
    const int US = (avail >= 4*psz) ? 4 : (avail >= 2*psz) ? 2 : 1;

    hipLaunchKernelGGL(prep_x, dim3((2*NZ*192 + 255)/256), dim3(256), 0, stream, x1, x2, XB1, XB2);
    hipLaunchKernelGGL(prep_w, dim3(11*64), dim3(256), 0, stream, W, Wtb);

    const int RED_GRID = NZ*576/4/256;     // 2304, exact
    if (US == 4) {
        hipLaunchKernelGGL(tp_main<4>, dim3(64*12), dim3(256), 0, stream, XB1, XB2, Wtb, Pbuf);
        hipLaunchKernelGGL(reduce_k<4>, dim3(RED_GRID), dim3(256), 0, stream, Pbuf, out);
    } else if (US == 2) {
        hipLaunchKernelGGL(tp_main<2>, dim3(64*6), dim3(256), 0, stream, XB1, XB2, Wtb, Pbuf);
        hipLaunchKernelGGL(reduce_k<2>, dim3(RED_GRID), dim3(256), 0, stream, Pbuf, out);
    } else {
        hipLaunchKernelGGL(tp_main<1>, dim3(64*3), dim3(256), 0, stream, XB1, XB2, Wtb, out);
    }
}